// Round 4
// baseline (11.959 us; speedup 1.0000x reference)
//
#include <hip/hip_runtime.h>

// Problem constants (from reference):
//   R=4, B=2048, S=10, U=20000, D=128
// Output: [R*B, D] fp32 = mean over the SET (dedup'd) of sampled neighbor embeddings.

#define RR 4
#define BB 2048
#define SS 10
#define UU 20000
#define DD 128
#define ROWS (RR * BB)          // 8192
#define NCHUNK 8                // column chunks of 16 floats, pinned to XCDs

typedef float vfloat4 __attribute__((ext_vector_type(4)));

// Grid: blockIdx & 7 = column chunk (16 floats) -> round-robin XCD dispatch
// keeps each XCD's gathers inside a 20000 x 64 B L2-resident slice.
// Block: 256 threads = 64 rows x 4 float4-lanes.
//
// KEY CHANGE vs round 3: all S gathers are issued UNCONDITIONALLY up front
// (indices are always valid; a duplicate load is harmless), so the compiler
// emits 10 back-to-back global_load_dwordx4 and one wait — instead of 10
// serialized {branch, load, waitcnt, add} blocks. Set semantics applied
// branchlessly via a 0/1 weight.
__global__ __launch_bounds__(256) void mean_agg_kernel(
    const int* __restrict__ neigh_idx,   // [ROWS, S]
    const float* __restrict__ embed,     // [U, D]
    float* __restrict__ out)             // [ROWS, D]
{
    const int chunk  = blockIdx.x & (NCHUNK - 1);
    const int group  = blockIdx.x >> 3;           // row group of 64
    const int tid    = threadIdx.x;
    const int slot   = tid >> 2;                  // 0..63
    const int c4l    = tid & 3;                   // 0..3
    const int row    = group * 64 + slot;
    const int col4   = chunk * 4 + c4l;           // float4 index within row

    // ---- indices, vectorized int2 (row*40 B is 8-B aligned) ----
    int id[SS];
    {
        const int2* ip2 = reinterpret_cast<const int2*>(neigh_idx + row * SS);
        #pragma unroll
        for (int j = 0; j < SS / 2; ++j) {
            const int2 p = ip2[j];
            id[2 * j]     = p.x;
            id[2 * j + 1] = p.y;
        }
    }

    // ---- issue ALL gathers unconditionally (maximal MLP, one drain) ----
    const vfloat4* __restrict__ esrc =
        reinterpret_cast<const vfloat4*>(embed) + col4;
    vfloat4 v[SS];
    #pragma unroll
    for (int j = 0; j < SS; ++j)
        v[j] = esrc[(size_t)id[j] * (DD / 4)];

    // ---- branchless set-dedup + accumulate ----
    vfloat4 acc = (vfloat4){0.f, 0.f, 0.f, 0.f};
    float cntf = 0.f;
    #pragma unroll
    for (int j = 0; j < SS; ++j) {
        bool dup = false;
        #pragma unroll
        for (int i = 0; i < j; ++i) dup = dup || (id[i] == id[j]);
        const float w = dup ? 0.f : 1.f;   // v_cndmask, no branch
        cntf += w;
        acc.x += v[j].x * w;
        acc.y += v[j].y * w;
        acc.z += v[j].z * w;
        acc.w += v[j].w * w;
    }
    acc *= (1.0f / cntf);                  // cnt >= 1 always (S >= 1)

    // Nontemporal: don't let the 4 MB output evict the embed slice from L2.
    __builtin_nontemporal_store(
        acc, reinterpret_cast<vfloat4*>(out) + (size_t)row * 32 + col4);
}

extern "C" void kernel_launch(void* const* d_in, const int* in_sizes, int n_in,
                              void* d_out, int out_size, void* d_ws, size_t ws_size,
                              hipStream_t stream) {
    const int*   neigh_idx = (const int*)d_in[0];    // [R,B,S] int32
    const float* embed     = (const float*)d_in[1];  // [U,D] fp32
    float*       out       = (float*)d_out;          // [ROWS, D] fp32

    const int block = 256;
    const int grid  = (ROWS / 64) * NCHUNK;          // 128 * 8 = 1024 blocks

    mean_agg_kernel<<<grid, block, 0, stream>>>(neigh_idx, embed, out);
}

// Round 5
// 10.180 us; speedup vs baseline: 1.1747x; 1.1747x over previous
//
#include <hip/hip_runtime.h>

// Problem constants (from reference):
//   R=4, B=2048, S=10, U=20000, D=128
// Output: [R*B, D] fp32 = mean over the SET (dedup'd) of sampled neighbor embeddings.

#define RR 4
#define BB 2048
#define SS 10
#define UU 20000
#define DD 128
#define ROWS (RR * BB)          // 8192
#define NCHUNK 8                // column chunks of 16 floats, pinned to XCDs
#define GROUPS (ROWS / 64)      // 128 row-groups per chunk
#define UPB ((UU + GROUPS - 1) / GROUPS)   // 157 table rows prefetched per block

typedef float vfloat4 __attribute__((ext_vector_type(4)));

// Round-2 winner geometry + cooperative L2 prefetch of the XCD's column slice.
//   blockIdx & 7  = column chunk (16 floats) -> round-robin XCD dispatch;
//                   each XCD's gathers stay inside a 20000 x 64 B = 1.28 MB
//                   L2-resident slice.
//   Each block first STREAMS its 1/128th of that slice linearly (coalesced
//   64 B segments, full DRAM efficiency) so the random gathers that follow
//   hit L2 instead of paying ~900-cycle random HBM reads on cold replays.
__global__ __launch_bounds__(256) void mean_agg_kernel(
    const int* __restrict__ neigh_idx,   // [ROWS, S]
    const float* __restrict__ embed,     // [U, D]
    float* __restrict__ out)             // [ROWS, D]
{
    const int chunk  = blockIdx.x & (NCHUNK - 1);
    const int group  = blockIdx.x >> 3;           // 0..127
    const int tid    = threadIdx.x;

    const vfloat4* __restrict__ ev = reinterpret_cast<const vfloat4*>(embed);

    // ---- cooperative prefetch: stream this block's share of the slice ----
    // Block covers table rows [group*UPB, (group+1)*UPB); each row contributes
    // 4 float4s (64 B) of this chunk's columns. 628 float4s / 256 threads.
    #pragma unroll
    for (int i = 0; i < (UPB * 4 + 255) / 256; ++i) {   // 3 iterations
        const int p = tid + i * 256;                    // 0..767
        const int u = group * UPB + (p >> 2);
        if (p < UPB * 4 && u < UU) {
            vfloat4 pf = ev[(size_t)u * (DD / 4) + chunk * 4 + (p & 3)];
            // keep the load alive without consuming it (no DCE)
            asm volatile("" :: "v"(pf.x), "v"(pf.y), "v"(pf.z), "v"(pf.w));
        }
    }

    // ---- round-2 winner body ----
    const int slot = tid >> 2;                    // 0..63
    const int c4l  = tid & 3;                     // 0..3
    const int row  = group * 64 + slot;
    const int col4 = chunk * 4 + c4l;             // float4 index within row

    int id[SS];
    {
        const int2* ip2 = reinterpret_cast<const int2*>(neigh_idx + row * SS);
        #pragma unroll
        for (int j = 0; j < SS / 2; ++j) {
            const int2 p = ip2[j];
            id[2 * j]     = p.x;
            id[2 * j + 1] = p.y;
        }
    }

    const vfloat4* __restrict__ esrc = ev + col4;

    vfloat4 acc = (vfloat4){0.f, 0.f, 0.f, 0.f};
    int cnt = 0;
    #pragma unroll
    for (int j = 0; j < SS; ++j) {
        bool dup = false;
        #pragma unroll
        for (int i = 0; i < j; ++i) dup = dup || (id[i] == id[j]);
        if (!dup) {
            ++cnt;
            acc += esrc[(size_t)id[j] * (DD / 4)];
        }
    }
    acc *= (1.0f / (float)cnt);                   // cnt >= 1 always

    __builtin_nontemporal_store(
        acc, reinterpret_cast<vfloat4*>(out) + (size_t)row * 32 + col4);
}

extern "C" void kernel_launch(void* const* d_in, const int* in_sizes, int n_in,
                              void* d_out, int out_size, void* d_ws, size_t ws_size,
                              hipStream_t stream) {
    const int*   neigh_idx = (const int*)d_in[0];    // [R,B,S] int32
    const float* embed     = (const float*)d_in[1];  // [U,D] fp32
    float*       out       = (float*)d_out;          // [ROWS, D] fp32

    const int block = 256;
    const int grid  = GROUPS * NCHUNK;               // 128 * 8 = 1024 blocks

    mean_agg_kernel<<<grid, block, 0, stream>>>(neigh_idx, embed, out);
}

// Round 6
// 9.869 us; speedup vs baseline: 1.2118x; 1.0316x over previous
//
#include <hip/hip_runtime.h>

// Problem constants (from reference):
//   R=4, B=2048, S=10, U=20000, D=128
// Output: [R*B, D] fp32 = mean over the SET (dedup'd) of sampled neighbor embeddings.
//
// FINAL (round-2 winner, re-instated): five structural variants (branchy
// gather, 2-rows/thread ILP, unconditional staged gathers, cooperative L2
// prefetch) all landed in 9.9-12.0 us. The kernel is at a launch + cold-cache
// floor: each timed replay runs after a 268 MB poison fill that wipes L2, so
// the ~10.6 MB table/index read + 4 MB write + dispatch ramp (~8-10 us total)
// is the binding constraint, not kernel structure.

#define RR 4
#define BB 2048
#define SS 10
#define UU 20000
#define DD 128
#define ROWS (RR * BB)          // 8192
#define NCHUNK 8                // column chunks of 16 floats, pinned to XCDs

typedef float vfloat4 __attribute__((ext_vector_type(4)));

// Grid decomposition: blockIdx & 7 = column chunk (16 floats) -> lands on one
// XCD via round-robin dispatch, so each XCD's L2 only holds a 20000 x 64 B
// = 1.28 MB slice of the embed table (fully L2-resident gathers).
// Block: 256 threads = 64 rows x 4 float4-lanes.
__global__ __launch_bounds__(256) void mean_agg_kernel(
    const int* __restrict__ neigh_idx,   // [ROWS, S]
    const float* __restrict__ embed,     // [U, D]
    float* __restrict__ out)             // [ROWS, D]
{
    const int chunk  = blockIdx.x & (NCHUNK - 1);
    const int group  = blockIdx.x >> 3;           // row group of 64
    const int tid    = threadIdx.x;
    const int slot   = tid >> 2;                  // 0..63
    const int c4l    = tid & 3;                   // 0..3
    const int row    = group * 64 + slot;
    const int col4   = chunk * 4 + c4l;           // float4 index within row

    // Row's S indices, vectorized int2 (row*40 B is 8-B aligned); 4 lanes per
    // row read the same 40 B (L1 broadcast).
    int id[SS];
    {
        const int2* ip2 = reinterpret_cast<const int2*>(neigh_idx + row * SS);
        #pragma unroll
        for (int j = 0; j < SS / 2; ++j) {
            const int2 p = ip2[j];
            id[2 * j]     = p.x;
            id[2 * j + 1] = p.y;
        }
    }

    const vfloat4* __restrict__ esrc =
        reinterpret_cast<const vfloat4*>(embed) + col4;

    vfloat4 acc = (vfloat4){0.f, 0.f, 0.f, 0.f};
    int cnt = 0;
    #pragma unroll
    for (int j = 0; j < SS; ++j) {
        // set semantics: keep j only if no earlier duplicate
        bool dup = false;
        #pragma unroll
        for (int i = 0; i < j; ++i) dup = dup || (id[i] == id[j]);
        if (!dup) {
            ++cnt;
            acc += esrc[(size_t)id[j] * (DD / 4)];
        }
    }
    // S>=1 so cnt>=1 always; reference's zero-guard can't trigger.
    acc *= (1.0f / (float)cnt);

    // Nontemporal: don't let the 4 MB output evict the embed slice from L2.
    __builtin_nontemporal_store(
        acc, reinterpret_cast<vfloat4*>(out) + (size_t)row * 32 + col4);
}

extern "C" void kernel_launch(void* const* d_in, const int* in_sizes, int n_in,
                              void* d_out, int out_size, void* d_ws, size_t ws_size,
                              hipStream_t stream) {
    const int*   neigh_idx = (const int*)d_in[0];    // [R,B,S] int32
    const float* embed     = (const float*)d_in[1];  // [U,D] fp32
    float*       out       = (float*)d_out;          // [ROWS, D] fp32

    const int block = 256;
    const int grid  = (ROWS / 64) * NCHUNK;          // 128 * 8 = 1024 blocks

    mean_agg_kernel<<<grid, block, 0, stream>>>(neigh_idx, embed, out);
}